// Round 16
// baseline (539.297 us; speedup 1.0000x reference)
//
#include <hip/hip_runtime.h>

// Problem constants (fixed by reference):
#define NB    32
#define CCH   256
#define HW    1024
#define NPIX  (NB*HW)     // 32768 pixels per input
#define DDICT 1024

#define EMB_ELEMS  ((size_t)NB*CCH*HW)      // 8388608
#define SEC_ELEMS  (2*EMB_ELEMS + NPIX)     // 16809984

// MFMA GEMM tiling — dict-split decomposition:
// block = 128 px x all 1024 dicts; 8 waves = 4 px-groups (32 px) x 2 dict-halves.
#define TPX  128           // pixels per block
#define TD   128           // dicts per staged tile
#define NDT  (DDICT/TD)    // 8 d-tiles
#define BK   32            // K per chunk (one 16x16x32 MFMA)
#define NKC  (CCH/BK)      // 8 chunks
#define NPH  (NDT*NKC)     // 64 staging phases

// Near-tie threshold (proven R8/R13 numerics): split error <= ~5e-3;
// 0.05 keeps ~10x margin. lambda ~4 flags/block.
#define TAU  0.05f

#define RB   8             // rescue: pixels batched per dictT sweep

typedef __attribute__((ext_vector_type(8))) short bf16x8;   // 8 bf16 = 4 VGPR
typedef __attribute__((ext_vector_type(4))) float f32x4;

// RNE round to bf16; returns bf16 bits, rest = exact residual.
__device__ inline ushort split_rne(float f, float& rest) {
    uint u = __float_as_uint(f);
    uint r = u + 0x7FFFu + ((u >> 16) & 1u);
    rest = f - __uint_as_float(r & 0xFFFF0000u);
    return (ushort)(r >> 16);
}

__device__ inline ushort rne_bf16(float f) {
    uint u = __float_as_uint(f);
    return (ushort)((u + 0x7FFFu + ((u >> 16) & 1u)) >> 16);
}

// async 16B global->LDS (linear dest: wave-uniform base + lane*16)
__device__ inline void gll16(const void* g, void* l) {
    __builtin_amdgcn_global_load_lds(
        (const __attribute__((address_space(1))) uint*)g,
        (__attribute__((address_space(3))) uint*)l,
        16, 0, 0);
}

// ---------------- Stage 0: dict prep (split + tile + transpose + norms) ------
// UNCHANGED from R13 (staging image identical; rescue needs dictT + norms).
__global__ void dict_prep_kernel(const float* __restrict__ dict,
                                 ushort* __restrict__ dHs,
                                 ushort* __restrict__ dMs,
                                 float* __restrict__ dictT,
                                 float* __restrict__ norms) {
    int d = blockIdx.x;
    int lane = threadIdx.x;   // 0..63
    float4 f = ((const float4*)(dict + (size_t)d * CCH))[lane];
    float v[4] = {f.x, f.y, f.z, f.w};
    ushort h[4], m[4];
#pragma unroll
    for (int i = 0; i < 4; ++i) {
        float r1;
        h[i] = split_rne(v[i], r1);
        m[i] = rne_bf16(r1);
    }
    int c0 = lane * 4;                        // 4 consecutive channels, one octet
    int kc = c0 >> 5, oct = (c0 >> 3) & 3, e0 = c0 & 7;
    int dt = d >> 7, dd = d & 127;
    int slot = (oct + (dd >> 1)) & 3;
    size_t base = ((size_t)(dt * NKC + kc)) * 4096 + dd * 32 + slot * 8 + e0;
    *(ushort4*)(dHs + base) = make_ushort4(h[0], h[1], h[2], h[3]);
    *(ushort4*)(dMs + base) = make_ushort4(m[0], m[1], m[2], m[3]);
#pragma unroll
    for (int j = 0; j < 4; ++j)
        dictT[(size_t)(c0 + j) * DDICT + d] = v[j];

    if (lane == 0) {          // verbatim dict_norms body (bit-identical chain)
        const float4* row = (const float4*)(dict + (size_t)d * CCH);
        float s = 0.f;
#pragma unroll 8
        for (int i = 0; i < CCH / 4; ++i) {
            float4 w = row[i];
            s += w.x * w.x + w.y * w.y + w.z * w.z + w.w * w.w;
        }
        norms[d] = s;
    }
}

// ---------------- Stage 1: megakernel — dict-split MFMA + merge + rescue -----
// Pipe accounting (R13): LDS-read 196k cyc/CU was the dominant demand (every
// wave read the FULL 16KB B-tile each phase). Dict-split halves it: wave
// (h = wv>>2, pg = wv&3) owns px [pg*32,+32) x dict-half h -> per phase it
// reads only its 4 dict-tiles (8KB, 8 ds_read_b128) for the same 24 MFMAs.
// Total waves unchanged (4/SIMD). Per-(pixel,dict) arithmetic verbatim; the
// cross-half (lex (dist,idx) + exact second-min) merge provably equals the
// sequential ascending top-2. Rescue = R13 verbatim per-block batched sweeps.
__global__ __launch_bounds__(512, 4)
void vq_mega_kernel(const float* __restrict__ x0,
                    const float* __restrict__ x1,
                    const ushort* __restrict__ dHs,
                    const ushort* __restrict__ dMs,
                    const float* __restrict__ norms,
                    const float* __restrict__ dict,
                    const float* __restrict__ dictT,
                    float* __restrict__ out) {
    __shared__ ushort Bs[2][2][4096];   // [buf][plane][8KB] 32 KB (xr overlay)
    __shared__ float nrm_s[DDICT];      // 4 KB (bitwise copy of norms)
    __shared__ int   idx_s[TPX];        // 512 B
    __shared__ int   fl_list[TPX];      // 512 B (per-block near-tie list)
    __shared__ int   fl_cnt;
    __shared__ float mg_b1[2][TPX];     // cross-half merge buffers, 3 KB
    __shared__ float mg_b2[2][TPX];
    __shared__ int   mg_i1[2][TPX];
    __shared__ float rd_s[8][RB];
    __shared__ int   ri_s[8][RB];
    __shared__ int   bi_s[RB];

    const int t    = threadIdx.x;       // 0..511
    const int lane = t & 63;
    const int wv   = t >> 6;            // 0..7
    const int h    = wv >> 2;           // dict-half (0: d<64 within tile)
    const int pg   = wv & 3;            // pixel-group
    const int lx   = lane & 15;         // MFMA row/col index
    const int q    = lane >> 4;         // k-octet / C-row quad
    const int m0w  = pg * 32;           // wave pixel offset (32 pixels/wave)
    const int z    = blockIdx.y;

    const int g0  = blockIdx.x * TPX;
    const int n   = g0 / HW;
    const int hw0 = g0 % HW;            // tile stays within one n (128 | 1024)

    const float* x = z ? x1 : x0;
    float* out_base = out + (size_t)z * SEC_ELEMS;
    float* out_emb    = out_base;
    float* out_emb_pt = out_base + EMB_ELEMS;
    float* out_idx    = out_base + 2 * EMB_ELEMS;

    if (t == 0) fl_cnt = 0;
    // norms -> LDS (bitwise copy; keeps the K-loop free of compiler VMEM)
    *(float2*)(nrm_s + t * 2) = *(const float2*)(norms + t * 2);

    // ---- A: direct coalesced fp32 reads of x + exact 2-way split, ONCE.
    //      32 px/wave (2 px-tiles); both halves read the same A (x2 HBM, ok).
    const float* xbase = x + (size_t)n * CCH * HW + hw0 + m0w + lx;
    bf16x8 Ah[8][2], Am[8][2];
#pragma unroll
    for (int kc = 0; kc < NKC; ++kc) {
        float a_f[2][8];
#pragma unroll
        for (int mi = 0; mi < 2; ++mi)
#pragma unroll
            for (int j = 0; j < 8; ++j)
                a_f[mi][j] = xbase[(size_t)(kc * BK + q * 8 + j) * HW + mi * 16];
#pragma unroll
        for (int mi = 0; mi < 2; ++mi)
#pragma unroll
            for (int j = 0; j < 8; ++j) {
                float r1;
                ushort hh = split_rne(a_f[mi][j], r1);
                Ah[kc][mi][j] = (short)hh;
                Am[kc][mi][j] = (short)rne_bf16(r1);
            }
    }

    // stage phase p (8KB x 2 planes = 16 KB): 2 gll16 per thread
    auto stage = [&](int p, int b) {
#pragma unroll
        for (int plane = 0; plane < 2; ++plane) {
            const ushort* sp = (plane ? dMs : dHs) + (size_t)p * 4096;
            gll16(sp + t * 8, &Bs[b][plane][wv * 512]);
        }
    };

    __syncthreads();          // nrm_s + fl_cnt visible
    stage(0, 0);

    // running top-2 per owned pixel-row (row = m0w + mi*16 + q*4 + r),
    // over this wave's dict-half only.
    float b1r[2][4], b2r[2][4]; int i1r[2][4];
#pragma unroll
    for (int mi = 0; mi < 2; ++mi)
#pragma unroll
        for (int r = 0; r < 4; ++r) {
            b1r[mi][r] = 3.0e38f; b2r[mi][r] = 3.0e38f; i1r[mi][r] = 0;
        }

    for (int dt = 0; dt < NDT; ++dt) {
        f32x4 acc[2][4] = {};            // [mi][ni] — 4 dict-tiles (this half)
#pragma unroll
        for (int kc = 0; kc < NKC; ++kc) {
            const int p = dt * 8 + kc;
            asm volatile("s_waitcnt vmcnt(0)" ::: "memory");  // stage(p) done
            __builtin_amdgcn_s_barrier();
            if (p + 1 < NPH) stage(p + 1, (p + 1) & 1);       // full-phase lead

            const ushort* bb = &Bs[p & 1][0][0];
            __builtin_amdgcn_s_setprio(1);
#pragma unroll
            for (int ni = 0; ni < 4; ++ni) {
                int nn   = h * 64 + ni * 16 + lx;
                int slot = (q + (nn >> 1)) & 3;
                int off  = nn * 32 + slot * 8;
                bf16x8 Bh = *(const bf16x8*)(bb + off);
                bf16x8 Bm = *(const bf16x8*)(bb + 4096 + off);
#pragma unroll
                for (int mi = 0; mi < 2; ++mi) {
                    f32x4 c = acc[mi][ni];
                    c = __builtin_amdgcn_mfma_f32_16x16x32_bf16(Ah[kc][mi], Bh, c, 0, 0, 0);
                    c = __builtin_amdgcn_mfma_f32_16x16x32_bf16(Ah[kc][mi], Bm, c, 0, 0, 0);
                    c = __builtin_amdgcn_mfma_f32_16x16x32_bf16(Am[kc][mi], Bh, c, 0, 0, 0);
                    acc[mi][ni] = c;
                }
            }
            __builtin_amdgcn_s_setprio(0);
        }

        // ---- per-tile epilogue: top-2 within this dict-half of the tile
        //      (insert order ni ascending = dict ascending within half; same
        //      comparison chain as R13), then running strict-< merge.
        const int d0 = dt * TD + h * 64;
        float nrm[4];
#pragma unroll
        for (int ni = 0; ni < 4; ++ni) nrm[ni] = nrm_s[d0 + ni * 16 + lx];

#pragma unroll
        for (int mi = 0; mi < 2; ++mi)
#pragma unroll
            for (int r = 0; r < 4; ++r) {
                float c1 = 3.0e38f, c2 = 3.0e38f; int ci = 0;
#pragma unroll
                for (int ni = 0; ni < 4; ++ni) {    // ascending dict within lane
                    float dist = fmaf(-2.f, acc[mi][ni][r], nrm[ni]);
                    if (dist < c1)      { c2 = c1; c1 = dist; ci = ni * 16 + lx; }
                    else if (dist < c2) { c2 = dist; }
                }
#pragma unroll
                for (int off = 1; off < 16; off <<= 1) {  // 16-lane, idx tie-break
                    float o1 = __shfl_xor(c1, off);
                    int   oi = __shfl_xor(ci, off);
                    float o2 = __shfl_xor(c2, off);
                    if (o1 < c1 || (o1 == c1 && oi < ci)) {
                        c2 = fminf(c1, o2); c1 = o1; ci = oi;
                    } else {
                        c2 = fminf(c2, o1);
                    }
                }
                if (c1 < b1r[mi][r]) {
                    b2r[mi][r] = fminf(b1r[mi][r], c2);
                    b1r[mi][r] = c1;
                    i1r[mi][r] = d0 + ci;
                } else {
                    b2r[mi][r] = fminf(b2r[mi][r], c1);
                }
            }
    }

    // ---- cross-half merge: exact lex (dist,idx) + exact second-min ---------
#pragma unroll
    for (int mi = 0; mi < 2; ++mi)
#pragma unroll
        for (int r = 0; r < 4; ++r) {
            if (lx == 0) {
                int row = m0w + mi * 16 + q * 4 + r;
                mg_b1[h][row] = b1r[mi][r];
                mg_i1[h][row] = i1r[mi][r];
                mg_b2[h][row] = b2r[mi][r];
            }
        }
    __syncthreads();

    if (t < TPX) {
        float b1a = mg_b1[0][t]; int i1a = mg_i1[0][t]; float b2a = mg_b2[0][t];
        float b1b = mg_b1[1][t]; int i1b = mg_i1[1][t]; float b2b = mg_b2[1][t];
        float b1, b2; int i1;
        if (b1b < b1a || (b1b == b1a && i1b < i1a)) {
            b1 = b1b; i1 = i1b; b2 = fminf(b2b, b1a);
        } else {
            b1 = b1a; i1 = i1a; b2 = fminf(b2a, b1b);
        }
        idx_s[t] = i1;
        out_idx[g0 + t] = (float)i1;
        if (b2 - b1 < TAU) {
            int s = atomicAdd(&fl_cnt, 1);            // LDS atomic
            fl_list[s] = t;
        }
    }
    __syncthreads();

    // ---- gather-transpose-write for this block's 128 pixels (R13 verbatim) -
    {
        const int pg2 = t & 31;   // 32 groups of 4 pixels
        const int cg  = t >> 5;   // 16 channel-groups of 16 channels
        const int hwp = hw0 + pg2 * 4;
        const float* r0 = dict + (size_t)idx_s[pg2 * 4 + 0] * CCH;
        const float* r1 = dict + (size_t)idx_s[pg2 * 4 + 1] * CCH;
        const float* r2 = dict + (size_t)idx_s[pg2 * 4 + 2] * CCH;
        const float* r3 = dict + (size_t)idx_s[pg2 * 4 + 3] * CCH;
        const size_t obase = (size_t)n * CCH * HW + hwp;
#pragma unroll
        for (int cq = 0; cq < 4; ++cq) {
            int c = cg * 16 + cq * 4;
            float4 q0 = *(const float4*)(r0 + c);
            float4 q1 = *(const float4*)(r1 + c);
            float4 q2 = *(const float4*)(r2 + c);
            float4 q3 = *(const float4*)(r3 + c);
            float4 v0 = make_float4(q0.x, q1.x, q2.x, q3.x);
            float4 v1 = make_float4(q0.y, q1.y, q2.y, q3.y);
            float4 v2 = make_float4(q0.z, q1.z, q2.z, q3.z);
            float4 v3 = make_float4(q0.w, q1.w, q2.w, q3.w);
            *(float4*)(out_emb    + obase + (size_t)(c + 0) * HW) = v0;
            *(float4*)(out_emb_pt + obase + (size_t)(c + 0) * HW) = v0;
            *(float4*)(out_emb    + obase + (size_t)(c + 1) * HW) = v1;
            *(float4*)(out_emb_pt + obase + (size_t)(c + 1) * HW) = v1;
            *(float4*)(out_emb    + obase + (size_t)(c + 2) * HW) = v2;
            *(float4*)(out_emb_pt + obase + (size_t)(c + 2) * HW) = v2;
            *(float4*)(out_emb    + obase + (size_t)(c + 3) * HW) = v3;
            *(float4*)(out_emb_pt + obase + (size_t)(c + 3) * HW) = v3;
        }
    }

    // ---- batched inline rescue: sweeps of RB pixels share one dictT pass ---
    // (R13 verbatim; xr overlaid on dead Bs buffer.)
    const int nf = fl_cnt;
    if (nf > 0) {
        float (*xr_)[CCH] = (float(*)[CCH])(&Bs[0][0][0]);   // 8 KB overlay
        for (int f0 = 0; f0 < nf; f0 += RB) {
            const int np = min(RB, nf - f0);
            __syncthreads();              // Bs/xr free (all prior readers past)
            {   // stage x: thread t loads 4 channels of pixel p = t>>6
                const int p  = t >> 6;
                const int pi = f0 + ((p < np) ? p : (np - 1));  // pad w/ last
                const int g  = g0 + fl_list[pi];
                const int hw = g % HW;
                const float* xb = x + (size_t)n * CCH * HW + hw;
                const int c0 = (t & 63) * 4;
#pragma unroll
                for (int j = 0; j < 4; ++j)
                    xr_[p][c0 + j] = xb[(size_t)(c0 + j) * HW];
            }
            __syncthreads();

            // one dictT sweep; thread t owns dicts {t, 512+t}
            float ac[2][RB] = {};
            for (int k = 0; k < CCH; ++k) {
                float xp[RB];
#pragma unroll
                for (int p = 0; p < RB; ++p) xp[p] = xr_[p][k];  // broadcast
#pragma unroll
                for (int dd = 0; dd < 2; ++dd) {
                    float v = dictT[(size_t)k * DDICT + dd * 512 + t];
#pragma unroll
                    for (int p = 0; p < RB; ++p)
                        ac[dd][p] = fmaf(xp[p], v, ac[dd][p]);
                }
            }
#pragma unroll
            for (int p = 0; p < RB; ++p) {
                float bd = 3.0e38f; int bi = 0;
#pragma unroll
                for (int dd = 0; dd < 2; ++dd) {      // ascending within thread
                    int d = dd * 512 + t;
                    float dist = fmaf(-2.f, ac[dd][p], nrm_s[d]);
                    if (dist < bd) { bd = dist; bi = d; }
                }
#pragma unroll
                for (int off = 1; off < 64; off <<= 1) {  // wave lex min
                    float od = __shfl_xor(bd, off);
                    int   oi = __shfl_xor(bi, off);
                    if (od < bd || (od == bd && oi < bi)) { bd = od; bi = oi; }
                }
                if (lane == 0) { rd_s[wv][p] = bd; ri_s[wv][p] = bi; }
            }
            __syncthreads();
            if (t < RB) {                 // t = pixel slot; 8-wave lex merge
                float fb = rd_s[0][t]; int fi = ri_s[0][t];
#pragma unroll
                for (int w2 = 1; w2 < 8; ++w2)
                    if (rd_s[w2][t] < fb ||
                        (rd_s[w2][t] == fb && ri_s[w2][t] < fi)) {
                        fb = rd_s[w2][t]; fi = ri_s[w2][t];
                    }
                bi_s[t] = fi;
                if (t < np) out_idx[g0 + fl_list[f0 + t]] = (float)fi;
            }
            __syncthreads();
            if (t < 256) {                // channel t, loop rescued pixels
                for (int p = 0; p < np; ++p) {
                    const int g  = g0 + fl_list[f0 + p];
                    const int hw = g % HW;
                    float v = dict[(size_t)bi_s[p] * CCH + t];
                    size_t o = (size_t)n * CCH * HW + (size_t)t * HW + hw;
                    out_emb[o]    = v;
                    out_emb_pt[o] = v;
                }
            }
        }
    }
}

extern "C" void kernel_launch(void* const* d_in, const int* in_sizes, int n_in,
                              void* d_out, int out_size, void* d_ws, size_t ws_size,
                              hipStream_t stream) {
    const float* x0   = (const float*)d_in[0];
    const float* x1   = (const float*)d_in[1];
    const float* dict = (const float*)d_in[2];
    float* out = (float*)d_out;

    // ws layout: norms 4K | dHs 512K | dMs 512K | dictT 1M
    float*  norms = (float*)d_ws;
    ushort* dHs   = (ushort*)(norms + DDICT);
    ushort* dMs   = dHs + (size_t)DDICT * CCH;
    float*  dictT = (float*)(dMs + (size_t)DDICT * CCH);

    dict_prep_kernel<<<dim3(DDICT), dim3(64), 0, stream>>>(dict, dHs, dMs,
                                                           dictT, norms);

    vq_mega_kernel<<<dim3(NPIX / TPX, 2), dim3(512), 0, stream>>>(
        x0, x1, dHs, dMs, norms, dict, dictT, out);
}

// Round 17
// 346.551 us; speedup vs baseline: 1.5562x; 1.5562x over previous
//
#include <hip/hip_runtime.h>

// Problem constants (fixed by reference):
#define NB    32
#define CCH   256
#define HW    1024
#define NPIX  (NB*HW)     // 32768 pixels per input
#define DDICT 1024

#define EMB_ELEMS  ((size_t)NB*CCH*HW)      // 8388608
#define SEC_ELEMS  (2*EMB_ELEMS + NPIX)     // 16809984

// MFMA GEMM tiling (R8 geometry + merged BK=64 phases)
#define TPX  128           // pixels per block (8 waves x 16 pixels)
#define TD   128           // dicts per tile
#define NDT  (DDICT/TD)    // 8 d-tiles (all processed by each block)
#define BK   32            // K per kc-chunk (one 16x16x32 MFMA)
#define NKC  (CCH/BK)      // 8 chunks per tile
#define NPH2 (NDT*NKC/2)   // 32 merged phases (2 chunks each)

// Near-tie threshold (R8/R13 numerics, proven): split error <= ~5e-3;
// 0.05 keeps ~10x margin. lambda ~4 flags/block.
#define TAU  0.05f

#define RB   8             // rescue: pixels batched per dictT sweep

typedef __attribute__((ext_vector_type(8))) short bf16x8;   // 8 bf16 = 4 VGPR
typedef __attribute__((ext_vector_type(4))) float f32x4;

// RNE round to bf16; returns bf16 bits, rest = exact residual.
__device__ inline ushort split_rne(float f, float& rest) {
    uint u = __float_as_uint(f);
    uint r = u + 0x7FFFu + ((u >> 16) & 1u);
    rest = f - __uint_as_float(r & 0xFFFF0000u);
    return (ushort)(r >> 16);
}

__device__ inline ushort rne_bf16(float f) {
    uint u = __float_as_uint(f);
    return (ushort)((u + 0x7FFFu + ((u >> 16) & 1u)) >> 16);
}

// async 16B global->LDS (linear dest: wave-uniform base + lane*16)
__device__ inline void gll16(const void* g, void* l) {
    __builtin_amdgcn_global_load_lds(
        (const __attribute__((address_space(1))) uint*)g,
        (__attribute__((address_space(3))) uint*)l,
        16, 0, 0);
}

// ---------------- Stage 0: dict prep (split + tile + transpose + norms) ------
// dHs/dMs: per (dt,kc) an 8KB chunk that IS the LDS image (swizzle baked in);
// consecutive kc-chunks are contiguous, so a BK=64 phase stages a 16KB pair
// with linear global_load_lds. dictT = fp32 transpose for the inline rescue.
__global__ void dict_prep_kernel(const float* __restrict__ dict,
                                 ushort* __restrict__ dHs,
                                 ushort* __restrict__ dMs,
                                 float* __restrict__ dictT,
                                 float* __restrict__ norms) {
    int d = blockIdx.x;
    int lane = threadIdx.x;   // 0..63
    float4 f = ((const float4*)(dict + (size_t)d * CCH))[lane];
    float v[4] = {f.x, f.y, f.z, f.w};
    ushort h[4], m[4];
#pragma unroll
    for (int i = 0; i < 4; ++i) {
        float r1;
        h[i] = split_rne(v[i], r1);
        m[i] = rne_bf16(r1);
    }
    int c0 = lane * 4;                        // 4 consecutive channels, one octet
    int kc = c0 >> 5, oct = (c0 >> 3) & 3, e0 = c0 & 7;
    int dt = d >> 7, dd = d & 127;
    int slot = (oct + (dd >> 1)) & 3;
    size_t base = ((size_t)(dt * NKC + kc)) * 4096 + dd * 32 + slot * 8 + e0;
    *(ushort4*)(dHs + base) = make_ushort4(h[0], h[1], h[2], h[3]);
    *(ushort4*)(dMs + base) = make_ushort4(m[0], m[1], m[2], m[3]);
#pragma unroll
    for (int j = 0; j < 4; ++j)
        dictT[(size_t)(c0 + j) * DDICT + d] = v[j];

    if (lane == 0) {          // verbatim dict_norms body (bit-identical chain)
        const float4* row = (const float4*)(dict + (size_t)d * CCH);
        float s = 0.f;
#pragma unroll 8
        for (int i = 0; i < CCH / 4; ++i) {
            float4 w = row[i];
            s += w.x * w.x + w.y * w.y + w.z * w.z + w.w * w.w;
        }
        norms[d] = s;
    }
}

// ---------------- Stage 1: megakernel — MFMA + top-2 + gather + batched rescue
// Best-measured configuration (R15, 347.4us): merged BK=64 phases (32 phases
// of {vmcnt(0); barrier; stage 32KB both planes with full-phase lead; 48
// MFMA/wave}), 16 px/wave x 8 waves, 4 waves/SIMD. Session conclusion: this
// sits at the closed LDS-amplification/VGPR/occupancy triangle — 16px/wave
// (196k cyc/CU ds_read demand) is the best reachable vertex; 32px/wave falls
// off the 128-VGPR occupancy cliff (R5: 180us), dict-split breaks staging L2
// locality (R16: FETCH x9). Rescue = per-block batched dictT sweeps (R13).
__global__ __launch_bounds__(512, 4)
void vq_mega_kernel(const float* __restrict__ x0,
                    const float* __restrict__ x1,
                    const ushort* __restrict__ dHs,
                    const ushort* __restrict__ dMs,
                    const float* __restrict__ norms,
                    const float* __restrict__ dict,
                    const float* __restrict__ dictT,
                    float* __restrict__ out) {
    __shared__ ushort Bs[2][2][8192];   // [buf][plane][16KB] 64 KB (xr overlay)
    __shared__ float nrm_s[DDICT];      // 4 KB (bitwise copy of norms)
    __shared__ int   idx_s[TPX];        // 512 B
    __shared__ int   fl_list[TPX];      // 512 B (per-block near-tie list)
    __shared__ int   fl_cnt;
    __shared__ float rd_s[8][RB];
    __shared__ int   ri_s[8][RB];
    __shared__ int   bi_s[RB];

    const int t    = threadIdx.x;       // 0..511
    const int lane = t & 63;
    const int wv   = t >> 6;            // 0..7
    const int lx   = lane & 15;         // MFMA row/col index
    const int q    = lane >> 4;         // k-octet / C-row quad
    const int m0w  = wv * 16;           // wave pixel offset (16 pixels/wave)
    const int z    = blockIdx.y;

    const int g0  = blockIdx.x * TPX;
    const int n   = g0 / HW;
    const int hw0 = g0 % HW;            // tile stays within one n (128 | 1024)

    const float* x = z ? x1 : x0;
    float* out_base = out + (size_t)z * SEC_ELEMS;
    float* out_emb    = out_base;
    float* out_emb_pt = out_base + EMB_ELEMS;
    float* out_idx    = out_base + 2 * EMB_ELEMS;

    if (t == 0) fl_cnt = 0;
    // norms -> LDS (bitwise copy; keeps the K-loop free of compiler VMEM)
    *(float2*)(nrm_s + t * 2) = *(const float2*)(norms + t * 2);

    // ---- A: direct coalesced fp32 reads of x + exact 2-way split, ONCE
    const float* xbase = x + (size_t)n * CCH * HW + hw0 + m0w + lx;
    bf16x8 Ah[8], Am[8];
#pragma unroll
    for (int kc = 0; kc < NKC; ++kc) {
        float a_f[8];
#pragma unroll
        for (int j = 0; j < 8; ++j)
            a_f[j] = xbase[(size_t)(kc * BK + q * 8 + j) * HW];
#pragma unroll
        for (int j = 0; j < 8; ++j) {
            float r1;
            ushort h = split_rne(a_f[j], r1);
            Ah[kc][j] = (short)h;
            Am[kc][j] = (short)rne_bf16(r1);
        }
    }

    // stage merged phase P (16KB x 2 planes = 32 KB): 4 gll16 per thread
    auto stage = [&](int P, int b) {
#pragma unroll
        for (int plane = 0; plane < 2; ++plane) {
            const ushort* sp = (plane ? dMs : dHs) + (size_t)P * 8192;
#pragma unroll
            for (int h = 0; h < 2; ++h) {
                gll16(sp + h * 4096 + t * 8,
                      &Bs[b][plane][h * 4096 + wv * 512]);
            }
        }
    };

    __syncthreads();          // nrm_s + fl_cnt visible
    stage(0, 0);

    // running top-2 per owned pixel-row (row = q*4 + r)
    float b1r[4], b2r[4]; int i1r[4];
#pragma unroll
    for (int r = 0; r < 4; ++r) {
        b1r[r] = 3.0e38f; b2r[r] = 3.0e38f; i1r[r] = 0;
    }

    for (int dt = 0; dt < NDT; ++dt) {
        f32x4 acc[8] = {};               // reset per tile (same as R13)
#pragma unroll
        for (int kh = 0; kh < 4; ++kh) {
            const int P = dt * 4 + kh;
            asm volatile("s_waitcnt vmcnt(0)" ::: "memory");  // stage(P) done
            __builtin_amdgcn_s_barrier();
            if (P + 1 < NPH2) stage(P + 1, (P + 1) & 1);      // full-phase lead

            const ushort* bb = &Bs[P & 1][0][0];
            __builtin_amdgcn_s_setprio(1);
#pragma unroll
            for (int ni = 0; ni < 8; ++ni) {
                int nn   = ni * 16 + lx;
                int slot = (q + (nn >> 1)) & 3;
                int off  = nn * 32 + slot * 8;
#pragma unroll
                for (int kk = 0; kk < 2; ++kk) {
                    const int kc = kh * 2 + kk;
                    bf16x8 Bh = *(const bf16x8*)(bb + kk * 4096 + off);
                    bf16x8 Bm = *(const bf16x8*)(bb + 8192 + kk * 4096 + off);
                    f32x4 c = acc[ni];
                    c = __builtin_amdgcn_mfma_f32_16x16x32_bf16(Ah[kc], Bh, c, 0, 0, 0);
                    c = __builtin_amdgcn_mfma_f32_16x16x32_bf16(Ah[kc], Bm, c, 0, 0, 0);
                    c = __builtin_amdgcn_mfma_f32_16x16x32_bf16(Am[kc], Bh, c, 0, 0, 0);
                    acc[ni] = c;
                }
            }
            __builtin_amdgcn_s_setprio(0);
        }

        // ---- per-tile epilogue: top-2 within tile, ascending strict-< merge
        //      (comparison/reduction order identical to R8/R13).
        const int d0 = dt * TD;
        float nrm[8];
#pragma unroll
        for (int ni = 0; ni < 8; ++ni) nrm[ni] = nrm_s[d0 + ni * 16 + lx];

#pragma unroll
        for (int r = 0; r < 4; ++r) {
            float c1 = 3.0e38f, c2 = 3.0e38f; int ci = 0;
#pragma unroll
            for (int ni = 0; ni < 8; ++ni) {        // ascending dict within lane
                float dist = fmaf(-2.f, acc[ni][r], nrm[ni]);
                if (dist < c1)      { c2 = c1; c1 = dist; ci = ni * 16 + lx; }
                else if (dist < c2) { c2 = dist; }
            }
#pragma unroll
            for (int off = 1; off < 16; off <<= 1) {  // 16-lane, idx tie-break
                float o1 = __shfl_xor(c1, off);
                int   oi = __shfl_xor(ci, off);
                float o2 = __shfl_xor(c2, off);
                if (o1 < c1 || (o1 == c1 && oi < ci)) {
                    c2 = fminf(c1, o2); c1 = o1; ci = oi;
                } else {
                    c2 = fminf(c2, o1);
                }
            }
            if (c1 < b1r[r]) {
                b2r[r] = fminf(b1r[r], c2);
                b1r[r] = c1;
                i1r[r] = d0 + ci;
            } else {
                b2r[r] = fminf(b2r[r], c1);
            }
        }
    }

    // ---- idx + per-block LDS flag list (no global atomics) ----
#pragma unroll
    for (int r = 0; r < 4; ++r) {
        if (lx == 0) {
            int loc = m0w + q * 4 + r;                // C-row = quad*4 + reg
            idx_s[loc] = i1r[r];
            out_idx[g0 + loc] = (float)i1r[r];
            if (b2r[r] - b1r[r] < TAU) {
                int s = atomicAdd(&fl_cnt, 1);        // LDS atomic
                fl_list[s] = loc;
            }
        }
    }
    __syncthreads();

    // ---- gather-transpose-write for this block's 128 pixels (R8 verbatim) --
    {
        const int pg = t & 31;    // 32 groups of 4 pixels
        const int cg = t >> 5;    // 16 channel-groups of 16 channels
        const int hwp = hw0 + pg * 4;
        const float* r0 = dict + (size_t)idx_s[pg * 4 + 0] * CCH;
        const float* r1 = dict + (size_t)idx_s[pg * 4 + 1] * CCH;
        const float* r2 = dict + (size_t)idx_s[pg * 4 + 2] * CCH;
        const float* r3 = dict + (size_t)idx_s[pg * 4 + 3] * CCH;
        const size_t obase = (size_t)n * CCH * HW + hwp;
#pragma unroll
        for (int cq = 0; cq < 4; ++cq) {
            int c = cg * 16 + cq * 4;
            float4 q0 = *(const float4*)(r0 + c);
            float4 q1 = *(const float4*)(r1 + c);
            float4 q2 = *(const float4*)(r2 + c);
            float4 q3 = *(const float4*)(r3 + c);
            float4 v0 = make_float4(q0.x, q1.x, q2.x, q3.x);
            float4 v1 = make_float4(q0.y, q1.y, q2.y, q3.y);
            float4 v2 = make_float4(q0.z, q1.z, q2.z, q3.z);
            float4 v3 = make_float4(q0.w, q1.w, q2.w, q3.w);
            *(float4*)(out_emb    + obase + (size_t)(c + 0) * HW) = v0;
            *(float4*)(out_emb_pt + obase + (size_t)(c + 0) * HW) = v0;
            *(float4*)(out_emb    + obase + (size_t)(c + 1) * HW) = v1;
            *(float4*)(out_emb_pt + obase + (size_t)(c + 1) * HW) = v1;
            *(float4*)(out_emb    + obase + (size_t)(c + 2) * HW) = v2;
            *(float4*)(out_emb_pt + obase + (size_t)(c + 2) * HW) = v2;
            *(float4*)(out_emb    + obase + (size_t)(c + 3) * HW) = v3;
            *(float4*)(out_emb_pt + obase + (size_t)(c + 3) * HW) = v3;
        }
    }

    // ---- batched inline rescue: sweeps of RB pixels share one dictT pass ---
    // (R13 verbatim; xr overlaid on dead Bs buffer.)
    const int nf = fl_cnt;
    if (nf > 0) {
        float (*xr_)[CCH] = (float(*)[CCH])(&Bs[0][0][0]);   // 8 KB overlay
        for (int f0 = 0; f0 < nf; f0 += RB) {
            const int np = min(RB, nf - f0);
            __syncthreads();              // Bs/xr free (all prior readers past)
            {   // stage x: thread t loads 4 channels of pixel p = t>>6
                const int p  = t >> 6;
                const int pi = f0 + ((p < np) ? p : (np - 1));  // pad w/ last
                const int g  = g0 + fl_list[pi];
                const int hw = g % HW;
                const float* xb = x + (size_t)n * CCH * HW + hw;
                const int c0 = (t & 63) * 4;
#pragma unroll
                for (int j = 0; j < 4; ++j)
                    xr_[p][c0 + j] = xb[(size_t)(c0 + j) * HW];
            }
            __syncthreads();

            // one dictT sweep; thread t owns dicts {t, 512+t}
            float ac[2][RB] = {};
            for (int k = 0; k < CCH; ++k) {
                float xp[RB];
#pragma unroll
                for (int p = 0; p < RB; ++p) xp[p] = xr_[p][k];  // broadcast
#pragma unroll
                for (int dd = 0; dd < 2; ++dd) {
                    float v = dictT[(size_t)k * DDICT + dd * 512 + t];
#pragma unroll
                    for (int p = 0; p < RB; ++p)
                        ac[dd][p] = fmaf(xp[p], v, ac[dd][p]);
                }
            }
#pragma unroll
            for (int p = 0; p < RB; ++p) {
                float bd = 3.0e38f; int bi = 0;
#pragma unroll
                for (int dd = 0; dd < 2; ++dd) {      // ascending within thread
                    int d = dd * 512 + t;
                    float dist = fmaf(-2.f, ac[dd][p], nrm_s[d]);
                    if (dist < bd) { bd = dist; bi = d; }
                }
#pragma unroll
                for (int off = 1; off < 64; off <<= 1) {  // wave lex min
                    float od = __shfl_xor(bd, off);
                    int   oi = __shfl_xor(bi, off);
                    if (od < bd || (od == bd && oi < bi)) { bd = od; bi = oi; }
                }
                if (lane == 0) { rd_s[wv][p] = bd; ri_s[wv][p] = bi; }
            }
            __syncthreads();
            if (t < RB) {                 // t = pixel slot; 8-wave lex merge
                float fb = rd_s[0][t]; int fi = ri_s[0][t];
#pragma unroll
                for (int w2 = 1; w2 < 8; ++w2)
                    if (rd_s[w2][t] < fb ||
                        (rd_s[w2][t] == fb && ri_s[w2][t] < fi)) {
                        fb = rd_s[w2][t]; fi = ri_s[w2][t];
                    }
                bi_s[t] = fi;
                if (t < np) out_idx[g0 + fl_list[f0 + t]] = (float)fi;
            }
            __syncthreads();
            if (t < 256) {                // channel t, loop rescued pixels
                for (int p = 0; p < np; ++p) {
                    const int g  = g0 + fl_list[f0 + p];
                    const int hw = g % HW;
                    float v = dict[(size_t)bi_s[p] * CCH + t];
                    size_t o = (size_t)n * CCH * HW + (size_t)t * HW + hw;
                    out_emb[o]    = v;
                    out_emb_pt[o] = v;
                }
            }
        }
    }
}

extern "C" void kernel_launch(void* const* d_in, const int* in_sizes, int n_in,
                              void* d_out, int out_size, void* d_ws, size_t ws_size,
                              hipStream_t stream) {
    const float* x0   = (const float*)d_in[0];
    const float* x1   = (const float*)d_in[1];
    const float* dict = (const float*)d_in[2];
    float* out = (float*)d_out;

    // ws layout: norms 4K | dHs 512K | dMs 512K | dictT 1M
    float*  norms = (float*)d_ws;
    ushort* dHs   = (ushort*)(norms + DDICT);
    ushort* dMs   = dHs + (size_t)DDICT * CCH;
    float*  dictT = (float*)(dMs + (size_t)DDICT * CCH);

    dict_prep_kernel<<<dim3(DDICT), dim3(64), 0, stream>>>(dict, dHs, dMs,
                                                           dictT, norms);

    vq_mega_kernel<<<dim3(NPIX / TPX, 2), dim3(512), 0, stream>>>(
        x0, x1, dHs, dMs, norms, dict, dictT, out);
}